// Round 15
// baseline (588.265 us; speedup 1.0000x reference)
//
#include <hip/hip_runtime.h>
#include <math.h>

#define N_NODES 100000
#define N_BASE  5000
#define N_EDGES 3200000
#define NBKT    782       // dest buckets of 128 nodes (3 sort-blocks/CU)
#define CAPB    5120      // csr slots per bucket (mean 4096, sigma 64 -> +16 sigma)
#define NEB     391       // edge blocks of 8192

// ---------------------------------------------------------------------------
// k_initg: gcur[b] = b*CAPB, bins = 0
// ---------------------------------------------------------------------------
__global__ __launch_bounds__(1024) void k_initg(int* __restrict__ gcur, float* __restrict__ bins) {
    int t = threadIdx.x;
    if (t < NBKT) gcur[t] = t * CAPB;
    if (t < 64) bins[t] = 0.0f;
}

// ---------------------------------------------------------------------------
// k_bucket (phase A): 391 blocks x 8192 edges. LDS histogram over 782 dest
// buckets -> chunked scan (4 slots/thread) -> one global chunk reservation
// per (block,bucket) -> direct chunked stores of packed (d&127)<<17 | src.
// ---------------------------------------------------------------------------
__global__ __launch_bounds__(256) void k_bucket(const int* __restrict__ row, const int* __restrict__ col,
                                                int* __restrict__ gcur, unsigned* __restrict__ csr) {
    __shared__ int hist[1024];                 // padded to 4*256, zeros beyond NBKT
    __shared__ int gbase[NBKT], cur[NBKT], exb[NBKT];
    __shared__ int tsum[256];
    int t = threadIdx.x;
    int e0 = blockIdx.x * 8192;
    int cnt = (N_EDGES - e0 < 8192) ? (N_EDGES - e0) : 8192;
    for (int k = t; k < 1024; k += 256) hist[k] = 0;
    __syncthreads();
    for (int j = t; j < cnt; j += 256) atomicAdd(&hist[col[e0 + j] >> 7], 1);
    __syncthreads();
    // chunked exclusive scan: thread t owns slots 4t..4t+3
    int b4 = t * 4;
    int s0 = hist[b4], s1 = hist[b4 + 1], s2 = hist[b4 + 2], s3 = hist[b4 + 3];
    int loc = s0 + s1 + s2 + s3;
    tsum[t] = loc;
    __syncthreads();
    for (int off = 1; off < 256; off <<= 1) {
        int v = (t >= off) ? tsum[t - off] : 0;
        __syncthreads();
        tsum[t] += v;
        __syncthreads();
    }
    int run = tsum[t] - loc;                   // exclusive prefix for this chunk
    int o0 = run, o1 = run + s0, o2 = o1 + s1, o3 = o2 + s2;
    if (b4 < NBKT)     { exb[b4] = o0;     cur[b4] = o0;     gbase[b4]     = (s0 > 0) ? atomicAdd(&gcur[b4], s0) : 0; }
    if (b4 + 1 < NBKT) { exb[b4 + 1] = o1; cur[b4 + 1] = o1; gbase[b4 + 1] = (s1 > 0) ? atomicAdd(&gcur[b4 + 1], s1) : 0; }
    if (b4 + 2 < NBKT) { exb[b4 + 2] = o2; cur[b4 + 2] = o2; gbase[b4 + 2] = (s2 > 0) ? atomicAdd(&gcur[b4 + 2], s2) : 0; }
    if (b4 + 3 < NBKT) { exb[b4 + 3] = o3; cur[b4 + 3] = o3; gbase[b4 + 3] = (s3 > 0) ? atomicAdd(&gcur[b4 + 3], s3) : 0; }
    __syncthreads();
    for (int j = t; j < cnt; j += 256) {
        int d = col[e0 + j];
        int s = row[e0 + j];
        int b = d >> 7;
        int slot = atomicAdd(&cur[b], 1);
        int local = slot - exb[b];
        csr[gbase[b] + local] = ((unsigned)(d & 127) << 17) | (unsigned)s;
    }
}

// ---------------------------------------------------------------------------
// k_sort (phase B): one block per 128-node bucket. LDS counting sort of
// <= CAPB edges by local dest; coalesced write-back of pure-src csr into the
// bucket's own window; emits rs/re (exact runs) and dinv (true degree).
// ---------------------------------------------------------------------------
__global__ __launch_bounds__(256) void k_sort(const int* __restrict__ gcur, unsigned* __restrict__ csr,
                                              int* __restrict__ rs, int* __restrict__ re,
                                              float* __restrict__ dinv) {
    __shared__ unsigned stage[CAPB];
    __shared__ int hist[128], offs[128], cur[128];
    int t = threadIdx.x, b = blockIdx.x;
    int base = b * CAPB;
    int cnt = gcur[b] - base;
    if (t < 128) hist[t] = 0;
    for (int j = t; j < cnt; j += 256) stage[j] = csr[base + j];
    __syncthreads();
    for (int j = t; j < cnt; j += 256) atomicAdd(&hist[stage[j] >> 17], 1);
    __syncthreads();
    if (t < 128) offs[t] = hist[t];
    __syncthreads();
    for (int off = 1; off < 128; off <<= 1) {
        int v = (t < 128 && t >= off) ? offs[t - off] : 0;
        __syncthreads();
        if (t < 128) offs[t] += v;
        __syncthreads();
    }
    if (t < 128) {
        int excl = offs[t] - hist[t];
        cur[t] = excl;
        int node = b * 128 + t;
        if (node < N_NODES) {
            rs[node] = base + excl;
            re[node] = base + excl + hist[t];
            dinv[node] = rsqrtf((float)(hist[t] + 1));   // +1 self loop
        }
    }
    __syncthreads();
    for (int j = t; j < cnt; j += 256) {
        unsigned p = stage[j];
        int slot = atomicAdd(&cur[p >> 17], 1);
        csr[base + slot] = p & 0x1FFFFu;             // pure src
    }
}

// ---------------------------------------------------------------------------
// k_ab_h: identical arithmetic to R12/R14 but weights read DIRECTLY from
// global (lane-uniform indices -> 1 broadcast line request, L2-hot) instead
// of LDS staging — removes the per-block staging serialization that left
// this kernel latency-bound at 1.5 blocks/CU. Bit-identical output.
// ---------------------------------------------------------------------------
__global__ __launch_bounds__(256) void k_ab_h(const float* __restrict__ x1, const float* __restrict__ x2,
                                              const float* __restrict__ W1, const float* __restrict__ b1,
                                              const float* __restrict__ W4, const float* __restrict__ b4,
                                              const float* __restrict__ Wg, const float* __restrict__ W3,
                                              const float* __restrict__ dinv,
                                              float* __restrict__ bb, float* __restrict__ h0,
                                              float* __restrict__ bins) {
    int i = blockIdx.x * 256 + threadIdx.x;
    bool valid = i < N_NODES;
    int ii = valid ? i : 0;
    float x[15];
#pragma unroll
    for (int k = 0; k < 15; k++) x[k] = x1[(size_t)ii * 15 + k];
    float xt[4];
    int ib = ii % N_BASE;
#pragma unroll
    for (int k = 0; k < 4; k++) xt[k] = x2[(size_t)ib * 4 + k];
    float in[34];
    float bp = 0.0f;
#pragma unroll
    for (int o = 0; o < 19; o++) {
        float s = b4[o];
#pragma unroll
        for (int k = 0; k < 15; k++) s += x[k] * W4[o * 19 + k];
#pragma unroll
        for (int k = 0; k < 4; k++) s += xt[k] * W4[o * 19 + 15 + k];
        in[15 + o] = s;
        bp += s * W3[15 + o];
    }
#pragma unroll
    for (int o = 0; o < 15; o++) {
        float s = b1[o];
#pragma unroll
        for (int k = 0; k < 15; k++) s += x[k] * W1[o * 15 + k];
        in[o] = fmaxf(s, 0.0f);
    }
    float dn = dinv[ii];
    if (valid) {
        float4* bbp = (float4*)(bb + (size_t)ii * 20);
        bbp[0] = make_float4(in[15], in[16], in[17], in[18]);
        bbp[1] = make_float4(in[19], in[20], in[21], in[22]);
        bbp[2] = make_float4(in[23], in[24], in[25], in[26]);
        bbp[3] = make_float4(in[27], in[28], in[29], in[30]);
        bbp[4] = make_float4(in[31], in[32], in[33], 0.0f);   // [19] pad, never consumed
        float hv[15];
#pragma unroll
        for (int o = 0; o < 15; o++) {
            float s = 0.0f;
#pragma unroll
            for (int k = 0; k < 34; k++) s += in[k] * Wg[o * 34 + k];
            hv[o] = s * dn;
        }
        float4* hp = (float4*)(h0 + (size_t)ii * 16);
        hp[0] = make_float4(hv[0], hv[1], hv[2], hv[3]);
        hp[1] = make_float4(hv[4], hv[5], hv[6], hv[7]);
        hp[2] = make_float4(hv[8], hv[9], hv[10], hv[11]);
        hp[3] = make_float4(hv[12], hv[13], hv[14], 0.0f);
    }
    float val = valid ? bp : 0.0f;
#pragma unroll
    for (int off = 32; off > 0; off >>= 1) val += __shfl_down(val, off, 64);
    __shared__ float wsum[4];
    if ((threadIdx.x & 63) == 0) wsum[threadIdx.x >> 6] = val;
    __syncthreads();
    if (threadIdx.x == 0) atomicAdd(&bins[blockIdx.x & 63], wsum[0] + wsum[1] + wsum[2] + wsum[3]);
}

// ---------------------------------------------------------------------------
// k_gather (R14 byte-frozen): one wave per dest node, 1024-thr blocks,
// tmp[16] independent predicated loads, ascending-order accumulate.
// At the measured line-service floor (~38 G random 64B lines/s).
// ---------------------------------------------------------------------------
__global__ __launch_bounds__(1024) void k_gather(const int* __restrict__ rs, const int* __restrict__ re,
                                                 const unsigned* __restrict__ csr,
                                                 const float* __restrict__ h_in,
                                                 const float* __restrict__ dinv,
                                                 const float* __restrict__ bb,
                                                 const float* __restrict__ Wg,
                                                 const float* __restrict__ bg,
                                                 const float* __restrict__ W3,
                                                 float* __restrict__ h_out,
                                                 float* __restrict__ bins, int last) {
    __shared__ float sWg[544], sbg[16], sW3[16];
    __shared__ float ws2[16];
    int t = threadIdx.x;
    for (int k = t; k < 544; k += 1024) sWg[k] = (k < 510) ? Wg[k] : 0.0f;
    if (t < 16) { sbg[t] = (t < 15) ? bg[t] : 0.0f; sW3[t] = (t < 15) ? W3[t] : 0.0f; }
    __syncthreads();
    int node = blockIdx.x * 16 + (t >> 6);
    int lane = t & 63, ch = lane & 15, q = lane >> 4;
    int start = rs[node];
    int deg = re[node] - start;
    float hs = h_in[(size_t)node * 16 + ch];   // self row, hoisted for overlap
    float acc = 0.0f;
    for (int base = 0; base < deg; base += 64) {
        int rem = deg - base;
        unsigned ce = 0;
        if (lane < rem) ce = csr[start + base + lane];
        int lim = rem < 64 ? rem : 64;
        float tmp[16];
#pragma unroll
        for (int i = 0; i < 16; i++) {
            int e0 = q + 4 * i;
            unsigned p = __shfl(ce, e0, 64);
            tmp[i] = (e0 < lim) ? h_in[(size_t)(p & 0x1FFFFu) * 16 + ch] : 0.0f;
        }
#pragma unroll
        for (int i = 0; i < 16; i++) acc += tmp[i];
    }
    acc += __shfl_xor(acc, 16, 64);
    acc += __shfl_xor(acc, 32, 64);
    float dn = dinv[node];
    float aval = fmaxf(dn * (hs + acc) + sbg[ch], 0.0f);   // a[ch]; ch==15 -> 0
    if (!last) {
        float ink[15];
#pragma unroll
        for (int k = 0; k < 15; k++) ink[k] = __shfl(aval, k, 64);
        const float4* bp4 = (const float4*)(bb + (size_t)node * 20);
        float4 q0 = bp4[0], q1 = bp4[1], q2 = bp4[2], q3 = bp4[3], q4 = bp4[4];
        float bv[19] = {q0.x, q0.y, q0.z, q0.w, q1.x, q1.y, q1.z, q1.w,
                        q2.x, q2.y, q2.z, q2.w, q3.x, q3.y, q3.z, q3.w,
                        q4.x, q4.y, q4.z};
        float s = 0.0f;
#pragma unroll
        for (int k = 0; k < 15; k++) s += ink[k] * sWg[ch * 34 + k];
#pragma unroll
        for (int k = 0; k < 19; k++) s += bv[k] * sWg[ch * 34 + 15 + k];
        if (q == 0) h_out[(size_t)node * 16 + ch] = s * dn;   // ch==15 row: sWg pad -> 0
    } else {
        float c = aval * sW3[ch];
        c += __shfl_xor(c, 8, 64);
        c += __shfl_xor(c, 4, 64);
        c += __shfl_xor(c, 2, 64);
        c += __shfl_xor(c, 1, 64);
        if (lane == 0) ws2[t >> 6] = c;
        __syncthreads();
        if (t == 0) {
            float s = 0.0f;
#pragma unroll
            for (int k = 0; k < 16; k++) s += ws2[k];
            atomicAdd(&bins[blockIdx.x & 63], s);
        }
    }
}

__global__ void k_finalize(const float* __restrict__ bins, const float* __restrict__ b3,
                           float* __restrict__ out) {
    float s = 0.0f;
    for (int k = 0; k < 64; k++) s += bins[k];
    out[0] = tanhf(s * (1.0f / (float)N_NODES) + b3[0]);
}

// ---------------------------------------------------------------------------
extern "C" void kernel_launch(void* const* d_in, const int* in_sizes, int n_in,
                              void* d_out, int out_size, void* d_ws, size_t ws_size,
                              hipStream_t stream) {
    const float* x1 = (const float*)d_in[0];
    const float* x2 = (const float*)d_in[1];
    const int* edges = (const int*)d_in[2];
    const float* W1 = (const float*)d_in[3];
    const float* b1 = (const float*)d_in[4];
    const float* Wg = (const float*)d_in[5];
    const float* bg = (const float*)d_in[6];
    const float* W3 = (const float*)d_in[7];
    const float* b3 = (const float*)d_in[8];
    const float* W4 = (const float*)d_in[9];
    const float* b4 = (const float*)d_in[10];

    const int* row = edges;             // edges[0]
    const int* col = edges + N_EDGES;   // edges[1]

    // workspace layout — ~38.4 MB (proven envelope >= 40.4 MB).
    char* ws = (char*)d_ws;
    unsigned* csr  = (unsigned*)ws;                              // NBKT*CAPB  (16.0 MB)
    float*    bb   = (float*)(csr + (size_t)NBKT * CAPB);        // N*20       (8.0 MB)
    float*    h0   = bb + (size_t)N_NODES * 20;                  // N*16       (6.4 MB)
    float*    h1   = h0 + (size_t)N_NODES * 16;                  // N*16       (6.4 MB)
    float*    dinv = h1 + (size_t)N_NODES * 16;                  // N
    int*      rs   = (int*)(dinv + N_NODES);                     // N
    int*      re   = rs + N_NODES;                               // N
    int*      gcur = re + N_NODES;                               // NBKT
    float*    bins = (float*)(gcur + NBKT);                      // 64

    int gN = (N_NODES + 255) / 256;                              // 391

    k_initg<<<1, 1024, 0, stream>>>(gcur, bins);
    k_bucket<<<NEB, 256, 0, stream>>>(row, col, gcur, csr);
    k_sort<<<NBKT, 256, 0, stream>>>(gcur, csr, rs, re, dinv);
    k_ab_h<<<gN, 256, 0, stream>>>(x1, x2, W1, b1, W4, b4, Wg, W3, dinv, bb, h0, bins);
    for (int t = 0; t < 5; t++) {
        const float* hi = (t & 1) ? h1 : h0;
        float* ho = (t & 1) ? h0 : h1;
        k_gather<<<N_NODES / 16, 1024, 0, stream>>>(rs, re, csr, hi, dinv, bb, Wg, bg, W3,
                                                    ho, bins, t == 4 ? 1 : 0);
    }
    k_finalize<<<1, 1, 0, stream>>>(bins, b3, (float*)d_out);
}

// Round 16
// 565.636 us; speedup vs baseline: 1.0400x; 1.0400x over previous
//
#include <hip/hip_runtime.h>
#include <math.h>

#define N_NODES 100000
#define N_BASE  5000
#define N_EDGES 3200000
#define NBKT    391       // dest buckets of 256 nodes; also = ceil(E/8192) edge blocks
#define CAPB    9472      // csr slots per bucket (mean 8184, sigma 90 -> +14 sigma)

// ---------------------------------------------------------------------------
// k_initg: gcur[b] = b*CAPB, bins = 0
// ---------------------------------------------------------------------------
__global__ __launch_bounds__(512) void k_initg(int* __restrict__ gcur, float* __restrict__ bins) {
    int t = threadIdx.x;
    if (t < NBKT) gcur[t] = t * CAPB;
    if (t < 64) bins[t] = 0.0f;
}

// ---------------------------------------------------------------------------
// k_bucket (phase A, R14 verbatim): 391 blocks x 8192 edges. LDS histogram
// over 391 dest buckets -> LDS scan -> one global chunk reservation per
// (block,bucket) -> direct chunked stores of packed (d&255)<<17 | src.
// ---------------------------------------------------------------------------
__global__ __launch_bounds__(256) void k_bucket(const int* __restrict__ row, const int* __restrict__ col,
                                                int* __restrict__ gcur, unsigned* __restrict__ csr) {
    __shared__ int hist[NBKT], gbase[NBKT], cur[NBKT];
    __shared__ int sc[512];
    int t = threadIdx.x;
    int e0 = blockIdx.x * 8192;
    int cnt = (N_EDGES - e0 < 8192) ? (N_EDGES - e0) : 8192;
    for (int k = t; k < NBKT; k += 256) hist[k] = 0;
    __syncthreads();
    for (int j = t; j < cnt; j += 256) atomicAdd(&hist[col[e0 + j] >> 8], 1);
    __syncthreads();
    // inclusive Hillis scan over 512 slots, 2 per thread
    sc[t] = (t < NBKT) ? hist[t] : 0;
    sc[t + 256] = (t + 256 < NBKT) ? hist[t + 256] : 0;
    __syncthreads();
    for (int off = 1; off < 512; off <<= 1) {
        int v0 = (t >= off) ? sc[t - off] : 0;
        int v1 = sc[t + 256 - off];          // t+256-off >= 0 since off <= 256
        __syncthreads();
        sc[t] += v0;
        sc[t + 256] += v1;
        __syncthreads();
    }
    for (int s = t; s < NBKT; s += 256) {
        cur[s] = sc[s] - hist[s];            // local exclusive offset
        gbase[s] = (hist[s] > 0) ? atomicAdd(&gcur[s], hist[s]) : 0;
    }
    __syncthreads();
    for (int j = t; j < cnt; j += 256) {
        int d = col[e0 + j];
        int s = row[e0 + j];
        int b = d >> 8;
        int slot = atomicAdd(&cur[b], 1);
        int local = slot - (sc[b] - hist[b]);
        csr[gbase[b] + local] = ((unsigned)(d & 255) << 17) | (unsigned)s;
    }
}

// ---------------------------------------------------------------------------
// k_sort (phase B, R14 verbatim): one block per bucket. LDS counting sort of
// <= CAPB edges by local dest; coalesced write-back of pure-src csr into the
// bucket's own window; emits rs/re (exact runs) and dinv (true degree).
// ---------------------------------------------------------------------------
__global__ __launch_bounds__(256) void k_sort(const int* __restrict__ gcur, unsigned* __restrict__ csr,
                                              int* __restrict__ rs, int* __restrict__ re,
                                              float* __restrict__ dinv) {
    __shared__ unsigned stage[CAPB];
    __shared__ int hist[256], offs[256], cur[256];
    int t = threadIdx.x, b = blockIdx.x;
    int base = b * CAPB;
    int cnt = gcur[b] - base;
    hist[t] = 0;
    for (int j = t; j < cnt; j += 256) stage[j] = csr[base + j];
    __syncthreads();
    for (int j = t; j < cnt; j += 256) atomicAdd(&hist[stage[j] >> 17], 1);
    __syncthreads();
    offs[t] = hist[t];
    __syncthreads();
    for (int off = 1; off < 256; off <<= 1) {
        int v = (t >= off) ? offs[t - off] : 0;
        __syncthreads();
        offs[t] += v;
        __syncthreads();
    }
    int excl = offs[t] - hist[t];
    cur[t] = excl;
    int node = b * 256 + t;
    if (node < N_NODES) {
        rs[node] = base + excl;
        re[node] = base + excl + hist[t];
        dinv[node] = rsqrtf((float)(hist[t] + 1));   // +1 self loop
    }
    __syncthreads();
    for (int j = t; j < cnt; j += 256) {
        unsigned p = stage[j];
        int slot = atomicAdd(&cur[p >> 17], 1);
        csr[base + slot] = p & 0x1FFFFu;             // pure src
    }
}

// ---------------------------------------------------------------------------
// k_ab_h (R15 version): identical arithmetic to R12/R14 but weights read
// DIRECTLY from global (lane-uniform indices -> scalar-cache broadcast,
// L2-hot) instead of LDS staging. Bit-identical output.
// ---------------------------------------------------------------------------
__global__ __launch_bounds__(256) void k_ab_h(const float* __restrict__ x1, const float* __restrict__ x2,
                                              const float* __restrict__ W1, const float* __restrict__ b1,
                                              const float* __restrict__ W4, const float* __restrict__ b4,
                                              const float* __restrict__ Wg, const float* __restrict__ W3,
                                              const float* __restrict__ dinv,
                                              float* __restrict__ bb, float* __restrict__ h0,
                                              float* __restrict__ bins) {
    int i = blockIdx.x * 256 + threadIdx.x;
    bool valid = i < N_NODES;
    int ii = valid ? i : 0;
    float x[15];
#pragma unroll
    for (int k = 0; k < 15; k++) x[k] = x1[(size_t)ii * 15 + k];
    float xt[4];
    int ib = ii % N_BASE;
#pragma unroll
    for (int k = 0; k < 4; k++) xt[k] = x2[(size_t)ib * 4 + k];
    float in[34];
    float bp = 0.0f;
#pragma unroll
    for (int o = 0; o < 19; o++) {
        float s = b4[o];
#pragma unroll
        for (int k = 0; k < 15; k++) s += x[k] * W4[o * 19 + k];
#pragma unroll
        for (int k = 0; k < 4; k++) s += xt[k] * W4[o * 19 + 15 + k];
        in[15 + o] = s;
        bp += s * W3[15 + o];
    }
#pragma unroll
    for (int o = 0; o < 15; o++) {
        float s = b1[o];
#pragma unroll
        for (int k = 0; k < 15; k++) s += x[k] * W1[o * 15 + k];
        in[o] = fmaxf(s, 0.0f);
    }
    float dn = dinv[ii];
    if (valid) {
        float4* bbp = (float4*)(bb + (size_t)ii * 20);
        bbp[0] = make_float4(in[15], in[16], in[17], in[18]);
        bbp[1] = make_float4(in[19], in[20], in[21], in[22]);
        bbp[2] = make_float4(in[23], in[24], in[25], in[26]);
        bbp[3] = make_float4(in[27], in[28], in[29], in[30]);
        bbp[4] = make_float4(in[31], in[32], in[33], 0.0f);   // [19] pad, never consumed
        float hv[15];
#pragma unroll
        for (int o = 0; o < 15; o++) {
            float s = 0.0f;
#pragma unroll
            for (int k = 0; k < 34; k++) s += in[k] * Wg[o * 34 + k];
            hv[o] = s * dn;
        }
        float4* hp = (float4*)(h0 + (size_t)ii * 16);
        hp[0] = make_float4(hv[0], hv[1], hv[2], hv[3]);
        hp[1] = make_float4(hv[4], hv[5], hv[6], hv[7]);
        hp[2] = make_float4(hv[8], hv[9], hv[10], hv[11]);
        hp[3] = make_float4(hv[12], hv[13], hv[14], 0.0f);
    }
    float val = valid ? bp : 0.0f;
#pragma unroll
    for (int off = 32; off > 0; off >>= 1) val += __shfl_down(val, off, 64);
    __shared__ float wsum[4];
    if ((threadIdx.x & 63) == 0) wsum[threadIdx.x >> 6] = val;
    __syncthreads();
    if (threadIdx.x == 0) atomicAdd(&bins[blockIdx.x & 63], wsum[0] + wsum[1] + wsum[2] + wsum[3]);
}

// ---------------------------------------------------------------------------
// k_gather (R14 byte-frozen): one wave per dest node, 1024-thr blocks,
// tmp[16] independent predicated loads, ascending-order accumulate.
// At the measured line-service floor (~38 G random 64B lines/s).
// ---------------------------------------------------------------------------
__global__ __launch_bounds__(1024) void k_gather(const int* __restrict__ rs, const int* __restrict__ re,
                                                 const unsigned* __restrict__ csr,
                                                 const float* __restrict__ h_in,
                                                 const float* __restrict__ dinv,
                                                 const float* __restrict__ bb,
                                                 const float* __restrict__ Wg,
                                                 const float* __restrict__ bg,
                                                 const float* __restrict__ W3,
                                                 float* __restrict__ h_out,
                                                 float* __restrict__ bins, int last) {
    __shared__ float sWg[544], sbg[16], sW3[16];
    __shared__ float ws2[16];
    int t = threadIdx.x;
    for (int k = t; k < 544; k += 1024) sWg[k] = (k < 510) ? Wg[k] : 0.0f;
    if (t < 16) { sbg[t] = (t < 15) ? bg[t] : 0.0f; sW3[t] = (t < 15) ? W3[t] : 0.0f; }
    __syncthreads();
    int node = blockIdx.x * 16 + (t >> 6);
    int lane = t & 63, ch = lane & 15, q = lane >> 4;
    int start = rs[node];
    int deg = re[node] - start;
    float hs = h_in[(size_t)node * 16 + ch];   // self row, hoisted for overlap
    float acc = 0.0f;
    for (int base = 0; base < deg; base += 64) {
        int rem = deg - base;
        unsigned ce = 0;
        if (lane < rem) ce = csr[start + base + lane];
        int lim = rem < 64 ? rem : 64;
        float tmp[16];
#pragma unroll
        for (int i = 0; i < 16; i++) {
            int e0 = q + 4 * i;
            unsigned p = __shfl(ce, e0, 64);
            tmp[i] = (e0 < lim) ? h_in[(size_t)(p & 0x1FFFFu) * 16 + ch] : 0.0f;
        }
#pragma unroll
        for (int i = 0; i < 16; i++) acc += tmp[i];
    }
    acc += __shfl_xor(acc, 16, 64);
    acc += __shfl_xor(acc, 32, 64);
    float dn = dinv[node];
    float aval = fmaxf(dn * (hs + acc) + sbg[ch], 0.0f);   // a[ch]; ch==15 -> 0
    if (!last) {
        float ink[15];
#pragma unroll
        for (int k = 0; k < 15; k++) ink[k] = __shfl(aval, k, 64);
        const float4* bp4 = (const float4*)(bb + (size_t)node * 20);
        float4 q0 = bp4[0], q1 = bp4[1], q2 = bp4[2], q3 = bp4[3], q4 = bp4[4];
        float bv[19] = {q0.x, q0.y, q0.z, q0.w, q1.x, q1.y, q1.z, q1.w,
                        q2.x, q2.y, q2.z, q2.w, q3.x, q3.y, q3.z, q3.w,
                        q4.x, q4.y, q4.z};
        float s = 0.0f;
#pragma unroll
        for (int k = 0; k < 15; k++) s += ink[k] * sWg[ch * 34 + k];
#pragma unroll
        for (int k = 0; k < 19; k++) s += bv[k] * sWg[ch * 34 + 15 + k];
        if (q == 0) h_out[(size_t)node * 16 + ch] = s * dn;   // ch==15 row: sWg pad -> 0
    } else {
        float c = aval * sW3[ch];
        c += __shfl_xor(c, 8, 64);
        c += __shfl_xor(c, 4, 64);
        c += __shfl_xor(c, 2, 64);
        c += __shfl_xor(c, 1, 64);
        if (lane == 0) ws2[t >> 6] = c;
        __syncthreads();
        if (t == 0) {
            float s = 0.0f;
#pragma unroll
            for (int k = 0; k < 16; k++) s += ws2[k];
            atomicAdd(&bins[blockIdx.x & 63], s);
        }
    }
}

__global__ void k_finalize(const float* __restrict__ bins, const float* __restrict__ b3,
                           float* __restrict__ out) {
    float s = 0.0f;
    for (int k = 0; k < 64; k++) s += bins[k];
    out[0] = tanhf(s * (1.0f / (float)N_NODES) + b3[0]);
}

// ---------------------------------------------------------------------------
extern "C" void kernel_launch(void* const* d_in, const int* in_sizes, int n_in,
                              void* d_out, int out_size, void* d_ws, size_t ws_size,
                              hipStream_t stream) {
    const float* x1 = (const float*)d_in[0];
    const float* x2 = (const float*)d_in[1];
    const int* edges = (const int*)d_in[2];
    const float* W1 = (const float*)d_in[3];
    const float* b1 = (const float*)d_in[4];
    const float* Wg = (const float*)d_in[5];
    const float* bg = (const float*)d_in[6];
    const float* W3 = (const float*)d_in[7];
    const float* b3 = (const float*)d_in[8];
    const float* W4 = (const float*)d_in[9];
    const float* b4 = (const float*)d_in[10];

    const int* row = edges;             // edges[0]
    const int* col = edges + N_EDGES;   // edges[1]

    // workspace layout — ~36.9 MB (proven envelope >= 40.4 MB).
    char* ws = (char*)d_ws;
    unsigned* csr  = (unsigned*)ws;                              // NBKT*CAPB  (14.81 MB)
    float*    bb   = (float*)(csr + (size_t)NBKT * CAPB);        // N*20       (8.0 MB)
    float*    h0   = bb + (size_t)N_NODES * 20;                  // N*16       (6.4 MB)
    float*    h1   = h0 + (size_t)N_NODES * 16;                  // N*16       (6.4 MB)
    float*    dinv = h1 + (size_t)N_NODES * 16;                  // N
    int*      rs   = (int*)(dinv + N_NODES);                     // N
    int*      re   = rs + N_NODES;                               // N
    int*      gcur = re + N_NODES;                               // NBKT
    float*    bins = (float*)(gcur + NBKT);                      // 64

    int gN = (N_NODES + 255) / 256;                              // 391
    int gE = (N_EDGES + 8191) / 8192;                            // 391

    k_initg<<<1, 512, 0, stream>>>(gcur, bins);
    k_bucket<<<gE, 256, 0, stream>>>(row, col, gcur, csr);
    k_sort<<<NBKT, 256, 0, stream>>>(gcur, csr, rs, re, dinv);
    k_ab_h<<<gN, 256, 0, stream>>>(x1, x2, W1, b1, W4, b4, Wg, W3, dinv, bb, h0, bins);
    for (int t = 0; t < 5; t++) {
        const float* hi = (t & 1) ? h1 : h0;
        float* ho = (t & 1) ? h0 : h1;
        k_gather<<<N_NODES / 16, 1024, 0, stream>>>(rs, re, csr, hi, dinv, bb, Wg, bg, W3,
                                                    ho, bins, t == 4 ? 1 : 0);
    }
    k_finalize<<<1, 1, 0, stream>>>(bins, b3, (float*)d_out);
}